// Round 1
// baseline (421.241 us; speedup 1.0000x reference)
//
#include <hip/hip_runtime.h>

typedef __attribute__((ext_vector_type(8))) short bf16x8;
typedef __attribute__((ext_vector_type(4))) float f32x4;
typedef unsigned short ushort_t;
typedef unsigned int uint32;

#define TILE 64
#define N_EDGES 1600000
#define NT (N_EDGES / TILE) /* 25000 */

// LDS geometry (in ushorts). Padded strides kill bank conflicts:
// CSTR=104 -> row step 52 dwords (mod 32 = 20): 8 distinct b128 bank-starts, 2 lanes/bank (free)
// HSTR=136 -> row step 68 dwords (mod 32 = 4):  8 distinct b128 bank-starts, 2 lanes/bank (free)
#define CSTR 104
#define HSTR 136
#define COL_OFF 0                       // collected [64][104]  (aliased with h)
#define H_OFF 0                         // h         [64][136]  (aliased with collected)
#define W1_OFF (TILE * HSTR)            // 8704:  W1t [128][104]
#define W2_OFF (W1_OFF + 128 * CSTR)    // 22016: W2t [32][136]
#define SMEM_USHORTS (W2_OFF + 32 * HSTR) // 26368 ushorts = 52736 B -> 3 blocks/CU

__device__ __forceinline__ ushort_t f2bf(float x) {
    uint32 u = __builtin_bit_cast(uint32, x);
    u += 0x7FFFu + ((u >> 16) & 1u);          // round-to-nearest-even
    return (ushort_t)(u >> 16);
}
__device__ __forceinline__ uint32 pack2(float a, float b) {
    return (uint32)f2bf(a) | ((uint32)f2bf(b) << 16);
}
__device__ __forceinline__ void store_bf16x8(ushort_t* dst, f32x4 a, f32x4 b) {
    uint4 p;
    p.x = pack2(a[0], a[1]);
    p.y = pack2(a[2], a[3]);
    p.z = pack2(b[0], b[1]);
    p.w = pack2(b[2], b[3]);
    *reinterpret_cast<uint4*>(dst) = p;
}

__global__ __launch_bounds__(256, 3)
void edge_mlp_kernel(const float* __restrict__ edge_feats,
                     const float* __restrict__ node_feats,
                     const int* __restrict__ senders,
                     const int* __restrict__ receivers,
                     const float* __restrict__ W1,
                     const float* __restrict__ b1,
                     const float* __restrict__ W2,
                     const float* __restrict__ b2,
                     float* __restrict__ out)
{
    __shared__ __align__(16) ushort_t smem[SMEM_USHORTS];
    ushort_t* colbuf = smem + COL_OFF;   // [64][CSTR] bf16 collected (edge|sender|receiver)
    ushort_t* hbuf   = smem + H_OFF;     // [64][HSTR] bf16 hidden (aliases colbuf)
    ushort_t* w1t    = smem + W1_OFF;    // [128][CSTR]  W1^T, k contiguous
    ushort_t* w2t    = smem + W2_OFF;    // [32][HSTR]   W2^T, n contiguous

    const int tid = threadIdx.x;
    const int l   = tid & 63;
    const int llo = l & 15;
    const int lhi = l >> 4;
    const int w   = tid >> 6;            // wave id 0..3, owns edges w*16..w*16+15 of the tile

    // ---- stage weights once per block (bf16, transposed so K is contiguous) ----
    for (int idx = tid; idx < 96 * 128; idx += 256) {
        int k = idx >> 7, n = idx & 127;               // W1[k][n], coalesced read
        w1t[n * CSTR + k] = f2bf(W1[idx]);
    }
    for (int idx = tid; idx < 128 * 32; idx += 256) {
        int n = idx >> 5, o = idx & 31;                // W2[n][o], coalesced read
        w2t[o * HSTR + n] = f2bf(W2[idx]);
    }

    // ---- bias fragments (match D-fragment lane layout: 4 consecutive at lhi*4) ----
    f32x4 b1v[8], b2v[2];
#pragma unroll
    for (int ni = 0; ni < 8; ++ni)
        b1v[ni] = *reinterpret_cast<const f32x4*>(b1 + ni * 16 + lhi * 4);
#pragma unroll
    for (int oi = 0; oi < 2; ++oi)
        b2v[oi] = *reinterpret_cast<const f32x4*>(b2 + oi * 16 + lhi * 4);

    const int row = tid >> 2;            // 0..63: edge within tile
    const int q   = tid & 3;             // 0..3: 8-float chunk within 32-feat vector

    for (int t = blockIdx.x; t < NT; t += gridDim.x) {
        const long e0 = (long)t * TILE;
        const long e  = e0 + row;

        // issue gathers early (registers only) so latency overlaps the barrier
        const int si = senders[e];
        const int ri = receivers[e];
        const f32x4* efp = reinterpret_cast<const f32x4*>(edge_feats + e * 32) + q * 2;
        f32x4 ea = efp[0], eb = efp[1];
        const f32x4* sp = reinterpret_cast<const f32x4*>(node_feats + (long)si * 32) + q * 2;
        f32x4 sa = sp[0], sb = sp[1];
        const f32x4* rp = reinterpret_cast<const f32x4*>(node_feats + (long)ri * 32) + q * 2;
        f32x4 ra = rp[0], rb = rp[1];

        __syncthreads();   // previous tile's h reads done (hbuf aliases colbuf)

        store_bf16x8(colbuf + row * CSTR +      q * 8, ea, eb);
        store_bf16x8(colbuf + row * CSTR + 32 + q * 8, sa, sb);
        store_bf16x8(colbuf + row * CSTR + 64 + q * 8, ra, rb);

        __syncthreads();

        // ---- GEMM1 (swapped): D = W1t x collected^T ; lane holds h[m=llo][n=ni*16+lhi*4+r]
        f32x4 acc1[8];
#pragma unroll
        for (int ni = 0; ni < 8; ++ni) acc1[ni] = f32x4{0.f, 0.f, 0.f, 0.f};
        const ushort_t* crow = colbuf + (w * 16 + llo) * CSTR + lhi * 8;
        const ushort_t* w1r  = w1t + llo * CSTR + lhi * 8;
#pragma unroll
        for (int kk = 0; kk < 3; ++kk) {
            bf16x8 bfrag = *reinterpret_cast<const bf16x8*>(crow + kk * 32);
#pragma unroll
            for (int ni = 0; ni < 8; ++ni) {
                bf16x8 afrag = *reinterpret_cast<const bf16x8*>(w1r + ni * 16 * CSTR + kk * 32);
                acc1[ni] = __builtin_amdgcn_mfma_f32_16x16x32_bf16(afrag, bfrag, acc1[ni], 0, 0, 0);
            }
        }

        __syncthreads();   // all collected reads complete before h overwrites the alias

        // ---- epilogue 1: bias + ReLU + pack bf16 -> h[m][n] via single b64 write
#pragma unroll
        for (int ni = 0; ni < 8; ++ni) {
            float h0 = fmaxf(acc1[ni][0] + b1v[ni][0], 0.f);
            float h1 = fmaxf(acc1[ni][1] + b1v[ni][1], 0.f);
            float h2 = fmaxf(acc1[ni][2] + b1v[ni][2], 0.f);
            float h3 = fmaxf(acc1[ni][3] + b1v[ni][3], 0.f);
            uint2 p;
            p.x = pack2(h0, h1);
            p.y = pack2(h2, h3);
            *reinterpret_cast<uint2*>(hbuf + (w * 16 + llo) * HSTR + ni * 16 + lhi * 4) = p;
        }

        __syncthreads();

        // ---- GEMM2 (swapped): D = W2t x h^T ; lane holds out[m=llo][o=oi*16+lhi*4+r]
        f32x4 acc2[2];
        acc2[0] = f32x4{0.f, 0.f, 0.f, 0.f};
        acc2[1] = f32x4{0.f, 0.f, 0.f, 0.f};
        const ushort_t* hrow = hbuf + (w * 16 + llo) * HSTR + lhi * 8;
        const ushort_t* w2r  = w2t + llo * HSTR + lhi * 8;
#pragma unroll
        for (int kk = 0; kk < 4; ++kk) {
            bf16x8 bfrag = *reinterpret_cast<const bf16x8*>(hrow + kk * 32);
#pragma unroll
            for (int oi = 0; oi < 2; ++oi) {
                bf16x8 afrag = *reinterpret_cast<const bf16x8*>(w2r + oi * 16 * HSTR + kk * 32);
                acc2[oi] = __builtin_amdgcn_mfma_f32_16x16x32_bf16(afrag, bfrag, acc2[oi], 0, 0, 0);
            }
        }

        // ---- epilogue 2: bias + coalesced dwordx4 store
        float* orow = out + (e0 + w * 16 + llo) * 32 + lhi * 4;
#pragma unroll
        for (int oi = 0; oi < 2; ++oi) {
            f32x4 r;
            r[0] = acc2[oi][0] + b2v[oi][0];
            r[1] = acc2[oi][1] + b2v[oi][1];
            r[2] = acc2[oi][2] + b2v[oi][2];
            r[3] = acc2[oi][3] + b2v[oi][3];
            *reinterpret_cast<f32x4*>(orow + oi * 16) = r;
        }
    }
}

extern "C" void kernel_launch(void* const* d_in, const int* in_sizes, int n_in,
                              void* d_out, int out_size, void* d_ws, size_t ws_size,
                              hipStream_t stream) {
    const float* edge_feats = (const float*)d_in[0];
    const float* node_feats = (const float*)d_in[1];
    const int*   senders    = (const int*)d_in[2];
    const int*   receivers  = (const int*)d_in[3];
    const float* W1         = (const float*)d_in[4];
    const float* b1         = (const float*)d_in[5];
    const float* W2         = (const float*)d_in[6];
    const float* b2         = (const float*)d_in[7];
    float* out = (float*)d_out;

    dim3 grid(2048), block(256);
    hipLaunchKernelGGL(edge_mlp_kernel, grid, block, 0, stream,
                       edge_feats, node_feats, senders, receivers, W1, b1, W2, b2, out);
}

// Round 2
// 388.417 us; speedup vs baseline: 1.0845x; 1.0845x over previous
//
#include <hip/hip_runtime.h>

typedef __attribute__((ext_vector_type(8))) short bf16x8;
typedef __attribute__((ext_vector_type(4))) float f32x4;
typedef unsigned short ushort_t;
typedef unsigned int uint32;

#define TILE 64
#define N_EDGES 1600000
#define NT (N_EDGES / TILE) /* 25000 */
#define GRID 768            /* 3 blocks/CU x 256 CU, LDS-capped occupancy */

// LDS geometry (ushorts). Per-wave private col/h buffer (aliased):
//   col [16][CSTR=104]  (1664 us)   h [16][HSTR=136] (2176 us)  -> WBUF=2176
// CSTR=104 -> b128 bank-starts (20*llo+4*lhi)&31: 8 accesses/bank = minimum (free)
// HSTR=136 -> b128 bank-starts (4*(llo+lhi))&31:  8 accesses/bank = minimum (free)
#define CSTR 104
#define HSTR 136
#define WBUF (16 * HSTR)                 /* 2176 ushorts per wave */
#define W1_OFF (4 * WBUF)                /* 8704 */
#define W2_OFF (W1_OFF + 128 * CSTR)     /* 22016 */
#define SMEM_USHORTS (W2_OFF + 32 * HSTR) /* 26368 ushorts = 52736 B -> 3 blocks/CU */

__device__ __forceinline__ ushort_t f2bf(float x) {
    uint32 u = __builtin_bit_cast(uint32, x);
    u += 0x7FFFu + ((u >> 16) & 1u);          // round-to-nearest-even
    return (ushort_t)(u >> 16);
}
__device__ __forceinline__ uint32 pack2(float a, float b) {
    return (uint32)f2bf(a) | ((uint32)f2bf(b) << 16);
}
__device__ __forceinline__ void store_bf16x8(ushort_t* dst, f32x4 a, f32x4 b) {
    uint4 p;
    p.x = pack2(a[0], a[1]);
    p.y = pack2(a[2], a[3]);
    p.z = pack2(b[0], b[1]);
    p.w = pack2(b[2], b[3]);
    *reinterpret_cast<uint4*>(dst) = p;
}

__global__ __launch_bounds__(256, 3)
void edge_mlp_kernel(const float* __restrict__ edge_feats,
                     const float* __restrict__ node_feats,
                     const int* __restrict__ senders,
                     const int* __restrict__ receivers,
                     const float* __restrict__ W1,
                     const float* __restrict__ b1,
                     const float* __restrict__ W2,
                     const float* __restrict__ b2,
                     float* __restrict__ out)
{
    __shared__ __align__(16) ushort_t smem[SMEM_USHORTS];
    ushort_t* w1t = smem + W1_OFF;    // [128][CSTR]  W1^T, k contiguous (shared, RO after barrier)
    ushort_t* w2t = smem + W2_OFF;    // [32][HSTR]   W2^T, n contiguous (shared, RO after barrier)

    const int tid = threadIdx.x;
    const int l   = tid & 63;
    const int llo = l & 15;
    const int lhi = l >> 4;
    const int w   = tid >> 6;            // wave id 0..3
    const int r   = l >> 2;              // 0..15: local edge row this thread stages
    const int q   = l & 3;               // 0..3: 8-float chunk within a 32-feat vector

    ushort_t* buf = smem + w * WBUF;     // per-wave private col/h (aliased) buffer

    // ---- stage weights once per block (bf16, transposed so K is contiguous) ----
    for (int idx = tid; idx < 96 * 128; idx += 256) {
        int k = idx >> 7, n = idx & 127;               // W1[k][n], coalesced read
        w1t[n * CSTR + k] = f2bf(W1[idx]);
    }
    for (int idx = tid; idx < 128 * 32; idx += 256) {
        int n = idx >> 5, o = idx & 31;                // W2[n][o], coalesced read
        w2t[o * HSTR + n] = f2bf(W2[idx]);
    }

    // ---- bias fragments (match D-fragment lane layout: 4 consecutive at lhi*4) ----
    f32x4 b1v[8], b2v[2];
#pragma unroll
    for (int ni = 0; ni < 8; ++ni)
        b1v[ni] = *reinterpret_cast<const f32x4*>(b1 + ni * 16 + lhi * 4);
#pragma unroll
    for (int oi = 0; oi < 2; ++oi)
        b2v[oi] = *reinterpret_cast<const f32x4*>(b2 + oi * 16 + lhi * 4);

    __syncthreads();   // the ONLY barrier: weights visible; everything after is wave-local

    const long stride = gridDim.x;
    const long last = (long)NT - 1;
    long t = blockIdx.x;

    // ---- software pipeline prologue: gathers(t) + indices(t+stride) in regs ----
    long eS = t * TILE + w * 16 + r;
    int si_c = senders[eS], ri_c = receivers[eS];
    f32x4 ea, eb, sa, sb, ra, rb;
    {
        const f32x4* efp = reinterpret_cast<const f32x4*>(edge_feats + eS * 32) + q * 2;
        ea = efp[0]; eb = efp[1];
        const f32x4* sp = reinterpret_cast<const f32x4*>(node_feats + (long)si_c * 32) + q * 2;
        sa = sp[0]; sb = sp[1];
        const f32x4* rp = reinterpret_cast<const f32x4*>(node_feats + (long)ri_c * 32) + q * 2;
        ra = rp[0]; rb = rp[1];
    }
    long ts1 = t + stride; ts1 = ts1 <= last ? ts1 : last;
    long eS1 = ts1 * TILE + w * 16 + r;
    int si_n = senders[eS1], ri_n = receivers[eS1];

    for (; t < NT; t += stride) {
        // ---- 1. stage col(t) from prefetched regs (wave-local LDS, no barrier) ----
        ushort_t* cw = buf + r * CSTR + q * 8;
        store_bf16x8(cw,      ea, eb);
        store_bf16x8(cw + 32, sa, sb);
        store_bf16x8(cw + 64, ra, rb);

        // ---- 2. issue gathers for t+stride (indices prefetched last iteration) ----
        long tn = t + stride; tn = tn <= last ? tn : last;
        f32x4 nea, neb, nsa, nsb, nra, nrb;
        {
            long eN = tn * TILE + w * 16 + r;
            const f32x4* efp = reinterpret_cast<const f32x4*>(edge_feats + eN * 32) + q * 2;
            nea = efp[0]; neb = efp[1];
            const f32x4* sp = reinterpret_cast<const f32x4*>(node_feats + (long)si_n * 32) + q * 2;
            nsa = sp[0]; nsb = sp[1];
            const f32x4* rp = reinterpret_cast<const f32x4*>(node_feats + (long)ri_n * 32) + q * 2;
            nra = rp[0]; nrb = rp[1];
        }
        // ---- 3. issue indices for t+2*stride ----
        long tn2 = t + 2 * stride; tn2 = tn2 <= last ? tn2 : last;
        long eN2 = tn2 * TILE + w * 16 + r;
        int si_2 = senders[eN2], ri_2 = receivers[eN2];

        // ---- 4. GEMM1 (swapped): lane holds h[edge=llo][n=ni*16+lhi*4+reg] ----
        f32x4 acc1[8];
#pragma unroll
        for (int ni = 0; ni < 8; ++ni) acc1[ni] = f32x4{0.f, 0.f, 0.f, 0.f};
        const ushort_t* crow = buf + llo * CSTR + lhi * 8;
        const ushort_t* w1r  = w1t + llo * CSTR + lhi * 8;
        __builtin_amdgcn_s_setprio(1);
#pragma unroll
        for (int kk = 0; kk < 3; ++kk) {
            bf16x8 bfrag = *reinterpret_cast<const bf16x8*>(crow + kk * 32);
#pragma unroll
            for (int ni = 0; ni < 8; ++ni) {
                bf16x8 afrag = *reinterpret_cast<const bf16x8*>(w1r + ni * 16 * CSTR + kk * 32);
                acc1[ni] = __builtin_amdgcn_mfma_f32_16x16x32_bf16(afrag, bfrag, acc1[ni], 0, 0, 0);
            }
        }
        __builtin_amdgcn_s_setprio(0);

        // ---- epilogue 1: bias + ReLU + pack bf16 -> h[m][n] (wave-local, no barrier) ----
#pragma unroll
        for (int ni = 0; ni < 8; ++ni) {
            float h0 = fmaxf(acc1[ni][0] + b1v[ni][0], 0.f);
            float h1 = fmaxf(acc1[ni][1] + b1v[ni][1], 0.f);
            float h2 = fmaxf(acc1[ni][2] + b1v[ni][2], 0.f);
            float h3 = fmaxf(acc1[ni][3] + b1v[ni][3], 0.f);
            uint2 p;
            p.x = pack2(h0, h1);
            p.y = pack2(h2, h3);
            *reinterpret_cast<uint2*>(buf + llo * HSTR + ni * 16 + lhi * 4) = p;
        }

        // ---- 5. GEMM2 (swapped): lane holds out[edge=llo][o=oi*16+lhi*4+reg] ----
        f32x4 acc2[2];
        acc2[0] = f32x4{0.f, 0.f, 0.f, 0.f};
        acc2[1] = f32x4{0.f, 0.f, 0.f, 0.f};
        const ushort_t* hrow = buf + llo * HSTR + lhi * 8;
        const ushort_t* w2r  = w2t + llo * HSTR + lhi * 8;
        __builtin_amdgcn_s_setprio(1);
#pragma unroll
        for (int kk = 0; kk < 4; ++kk) {
            bf16x8 bfrag = *reinterpret_cast<const bf16x8*>(hrow + kk * 32);
#pragma unroll
            for (int oi = 0; oi < 2; ++oi) {
                bf16x8 afrag = *reinterpret_cast<const bf16x8*>(w2r + oi * 16 * HSTR + kk * 32);
                acc2[oi] = __builtin_amdgcn_mfma_f32_16x16x32_bf16(afrag, bfrag, acc2[oi], 0, 0, 0);
            }
        }
        __builtin_amdgcn_s_setprio(0);

        // ---- epilogue 2: bias + coalesced dwordx4 store ----
        float* orow = out + (t * TILE + w * 16 + llo) * 32 + lhi * 4;
#pragma unroll
        for (int oi = 0; oi < 2; ++oi) {
            f32x4 rr;
            rr[0] = acc2[oi][0] + b2v[oi][0];
            rr[1] = acc2[oi][1] + b2v[oi][1];
            rr[2] = acc2[oi][2] + b2v[oi][2];
            rr[3] = acc2[oi][3] + b2v[oi][3];
            *reinterpret_cast<f32x4*>(orow + oi * 16) = rr;
        }

        // ---- 6. rotate pipeline regs ----
        ea = nea; eb = neb; sa = nsa; sb = nsb; ra = nra; rb = nrb;
        si_n = si_2; ri_n = ri_2;
    }
}

extern "C" void kernel_launch(void* const* d_in, const int* in_sizes, int n_in,
                              void* d_out, int out_size, void* d_ws, size_t ws_size,
                              hipStream_t stream) {
    const float* edge_feats = (const float*)d_in[0];
    const float* node_feats = (const float*)d_in[1];
    const int*   senders    = (const int*)d_in[2];
    const int*   receivers  = (const int*)d_in[3];
    const float* W1         = (const float*)d_in[4];
    const float* b1         = (const float*)d_in[5];
    const float* W2         = (const float*)d_in[6];
    const float* b2         = (const float*)d_in[7];
    float* out = (float*)d_out;

    dim3 grid(GRID), block(256);
    hipLaunchKernelGGL(edge_mlp_kernel, grid, block, 0, stream,
                       edge_feats, node_feats, senders, receivers, W1, b1, W2, b2, out);
}

// Round 5
// 381.828 us; speedup vs baseline: 1.1032x; 1.0173x over previous
//
#include <hip/hip_runtime.h>

typedef __attribute__((ext_vector_type(8))) short bf16x8;
typedef __attribute__((ext_vector_type(4))) float f32x4;
typedef unsigned short ushort_t;
typedef unsigned int uint32;

#define TILE 64
#define N_EDGES 1600000
#define NT (N_EDGES / TILE) /* 25000 */
#define GRID 512            /* 2 blocks/CU x 256 CU (VGPR-capped occupancy) */

// LDS (ushorts). Weight staging region (used once, then dead) overlaps the
// per-wave col/h buffers used in the main loop.
// CSTR=104: b128 bank-starts (20*llo+4*lhi)&31 uniform -> conflict-free
// HSTR=136: b128 bank-starts (4*(llo+lhi))&31 uniform -> conflict-free
#define CSTR 104
#define HSTR 136
#define W1_US (128 * CSTR)              /* 13312 us: W1^T staging */
#define W2_US (32 * HSTR)               /* 4352 us:  W2^T staging */
#define WEIGHT_US (W1_US + W2_US)       /* 17664 us = 35328 B */
#define WBUF (16 * HSTR)                /* 2176 us per-wave aliased col/h buffer */
#define SMEM_USHORTS WEIGHT_US          /* 35328 B; wave bufs (4*2176=8704 us) alias low part */

__device__ __forceinline__ ushort_t f2bf(float x) {
    uint32 u = __builtin_bit_cast(uint32, x);
    u += 0x7FFFu + ((u >> 16) & 1u);          // round-to-nearest-even
    return (ushort_t)(u >> 16);
}
__device__ __forceinline__ uint32 pack2(float a, float b) {
    return (uint32)f2bf(a) | ((uint32)f2bf(b) << 16);
}
__device__ __forceinline__ void store_bf16x8(ushort_t* dst, f32x4 a, f32x4 b) {
    uint4 p;
    p.x = pack2(a[0], a[1]);
    p.y = pack2(a[2], a[3]);
    p.z = pack2(b[0], b[1]);
    p.w = pack2(b[2], b[3]);
    *reinterpret_cast<uint4*>(dst) = p;
}

__global__ __launch_bounds__(256, 2)
void edge_mlp_kernel(const float* __restrict__ edge_feats,
                     const float* __restrict__ node_feats,
                     const int* __restrict__ senders,
                     const int* __restrict__ receivers,
                     const float* __restrict__ W1,
                     const float* __restrict__ b1,
                     const float* __restrict__ W2,
                     const float* __restrict__ b2,
                     float* __restrict__ out)
{
    __shared__ __align__(16) ushort_t smem[SMEM_USHORTS];

    const int tid = threadIdx.x;
    const int l   = tid & 63;
    const int llo = l & 15;
    const int lhi = l >> 4;
    const int w   = tid >> 6;            // wave id 0..3
    const int r   = l >> 2;              // 0..15: local edge row this thread stages
    const int q   = l & 3;               // 0..3: 8-float chunk within a 32-feat vector

    // ================= one-time: stage weights to LDS, pull frags to REGISTERS =================
    {
        ushort_t* w1t = smem;            // [128][CSTR], k contiguous
        ushort_t* w2t = smem + W1_US;    // [32][HSTR],  n contiguous
        for (int idx = tid; idx < 96 * 128; idx += 256) {
            int k = idx >> 7, n = idx & 127;               // W1[k][n], coalesced read
            w1t[n * CSTR + k] = f2bf(W1[idx]);
        }
        for (int idx = tid; idx < 128 * 32; idx += 256) {
            int n = idx >> 5, o = idx & 31;                // W2[n][o], coalesced read
            w2t[o * HSTR + n] = f2bf(W2[idx]);
        }
    }
    __syncthreads();

    // A-fragment registers (loop-invariant): lane holds W^T[16*i+llo][kk*32+lhi*8 ..+8]
    bf16x8 w1f[8][3];
#pragma unroll
    for (int ni = 0; ni < 8; ++ni)
#pragma unroll
        for (int kk = 0; kk < 3; ++kk)
            w1f[ni][kk] = *reinterpret_cast<const bf16x8*>(
                smem + (ni * 16 + llo) * CSTR + kk * 32 + lhi * 8);
    bf16x8 w2f[2][4];
#pragma unroll
    for (int oi = 0; oi < 2; ++oi)
#pragma unroll
        for (int kk = 0; kk < 4; ++kk)
            w2f[oi][kk] = *reinterpret_cast<const bf16x8*>(
                smem + W1_US + (oi * 16 + llo) * HSTR + kk * 32 + lhi * 8);

    // bias fragments, used as accumulator INIT (C-in of first MFMA)
    f32x4 b1v[8], b2v[2];
#pragma unroll
    for (int ni = 0; ni < 8; ++ni)
        b1v[ni] = *reinterpret_cast<const f32x4*>(b1 + ni * 16 + lhi * 4);
#pragma unroll
    for (int oi = 0; oi < 2; ++oi)
        b2v[oi] = *reinterpret_cast<const f32x4*>(b2 + oi * 16 + lhi * 4);

    __syncthreads();   // weight LDS now dead; region reused as per-wave buffers

    ushort_t* buf = smem + w * WBUF;     // per-wave private col/h (aliased) buffer

    const long stride = gridDim.x;
    const long last = (long)NT - 1;
    long t = blockIdx.x;

    // ---- software pipeline prologue: gathers(t) + indices(t+stride) in regs ----
    long eS = t * TILE + w * 16 + r;
    int si_c = senders[eS], ri_c = receivers[eS];
    f32x4 ea, eb, sa, sb, ra, rb;
    {
        const f32x4* efp = reinterpret_cast<const f32x4*>(edge_feats + eS * 32) + q * 2;
        ea = efp[0]; eb = efp[1];
        const f32x4* sp = reinterpret_cast<const f32x4*>(node_feats + (long)si_c * 32) + q * 2;
        sa = sp[0]; sb = sp[1];
        const f32x4* rp = reinterpret_cast<const f32x4*>(node_feats + (long)ri_c * 32) + q * 2;
        ra = rp[0]; rb = rp[1];
    }
    long ts1 = t + stride; ts1 = ts1 <= last ? ts1 : last;
    long eS1 = ts1 * TILE + w * 16 + r;
    int si_n = senders[eS1], ri_n = receivers[eS1];

    for (; t < NT; t += stride) {
        // ---- 1. stage col(t) from prefetched regs (wave-local LDS, no barrier) ----
        ushort_t* cw = buf + r * CSTR + q * 8;
        store_bf16x8(cw,      ea, eb);
        store_bf16x8(cw + 32, sa, sb);
        store_bf16x8(cw + 64, ra, rb);

        // ---- 2. issue gathers for t+stride (indices prefetched last iteration) ----
        long tn = t + stride; tn = tn <= last ? tn : last;
        {
            long eN = tn * TILE + w * 16 + r;
            const f32x4* efp = reinterpret_cast<const f32x4*>(edge_feats + eN * 32) + q * 2;
            ea = efp[0]; eb = efp[1];   // safe: cur values already staged to LDS above
            const f32x4* sp = reinterpret_cast<const f32x4*>(node_feats + (long)si_n * 32) + q * 2;
            sa = sp[0]; sb = sp[1];
            const f32x4* rp = reinterpret_cast<const f32x4*>(node_feats + (long)ri_n * 32) + q * 2;
            ra = rp[0]; rb = rp[1];
        }
        // ---- 3. issue indices for t+2*stride ----
        long tn2 = t + 2 * stride; tn2 = tn2 <= last ? tn2 : last;
        long eN2 = tn2 * TILE + w * 16 + r;
        si_n = senders[eN2]; ri_n = receivers[eN2];

        // ---- 4. GEMM1 (swapped, A in regs): lane -> h[edge=llo][n=ni*16+lhi*4+j] ----
        f32x4 acc1[8];
#pragma unroll
        for (int ni = 0; ni < 8; ++ni) acc1[ni] = b1v[ni];   // bias as C-in
        const ushort_t* crow = buf + llo * CSTR + lhi * 8;
        __builtin_amdgcn_s_setprio(1);
#pragma unroll
        for (int kk = 0; kk < 3; ++kk) {
            bf16x8 bfrag = *reinterpret_cast<const bf16x8*>(crow + kk * 32);
#pragma unroll
            for (int ni = 0; ni < 8; ++ni)
                acc1[ni] = __builtin_amdgcn_mfma_f32_16x16x32_bf16(w1f[ni][kk], bfrag, acc1[ni], 0, 0, 0);
        }
        __builtin_amdgcn_s_setprio(0);

        // ---- epilogue 1: ReLU + pack bf16 -> h[m][n] (wave-local, no barrier) ----
#pragma unroll
        for (int ni = 0; ni < 8; ++ni) {
            float h0 = fmaxf(acc1[ni][0], 0.f);
            float h1 = fmaxf(acc1[ni][1], 0.f);
            float h2 = fmaxf(acc1[ni][2], 0.f);
            float h3 = fmaxf(acc1[ni][3], 0.f);
            uint2 p;
            p.x = pack2(h0, h1);
            p.y = pack2(h2, h3);
            *reinterpret_cast<uint2*>(buf + llo * HSTR + ni * 16 + lhi * 4) = p;
        }

        // ---- 5. GEMM2 (swapped, A in regs): lane -> out[edge=llo][o=oi*16+lhi*4+j] ----
        f32x4 acc2[2];
        acc2[0] = b2v[0];
        acc2[1] = b2v[1];
        const ushort_t* hrow = buf + llo * HSTR + lhi * 8;
        __builtin_amdgcn_s_setprio(1);
#pragma unroll
        for (int kk = 0; kk < 4; ++kk) {
            bf16x8 bfrag = *reinterpret_cast<const bf16x8*>(hrow + kk * 32);
#pragma unroll
            for (int oi = 0; oi < 2; ++oi)
                acc2[oi] = __builtin_amdgcn_mfma_f32_16x16x32_bf16(w2f[oi][kk], bfrag, acc2[oi], 0, 0, 0);
        }
        __builtin_amdgcn_s_setprio(0);

        // ---- epilogue 2: coalesced dwordx4 store ----
        float* orow = out + (t * TILE + w * 16 + llo) * 32 + lhi * 4;
        *reinterpret_cast<f32x4*>(orow)      = acc2[0];
        *reinterpret_cast<f32x4*>(orow + 16) = acc2[1];
    }
}

extern "C" void kernel_launch(void* const* d_in, const int* in_sizes, int n_in,
                              void* d_out, int out_size, void* d_ws, size_t ws_size,
                              hipStream_t stream) {
    const float* edge_feats = (const float*)d_in[0];
    const float* node_feats = (const float*)d_in[1];
    const int*   senders    = (const int*)d_in[2];
    const int*   receivers  = (const int*)d_in[3];
    const float* W1         = (const float*)d_in[4];
    const float* b1         = (const float*)d_in[5];
    const float* W2         = (const float*)d_in[6];
    const float* b2         = (const float*)d_in[7];
    float* out = (float*)d_out;

    dim3 grid(GRID), block(256);
    hipLaunchKernelGGL(edge_mlp_kernel, grid, block, 0, stream,
                       edge_feats, node_feats, senders, receivers, W1, b1, W2, b2, out);
}